// Round 10
// baseline (305.944 us; speedup 1.0000x reference)
//
#include <hip/hip_runtime.h>
#include <math.h>

#define NNT 48
#define LL 32
#define BB 32
#define N2 2304            // 48*48
#define KSTEPS 72          // 2304/32
#define EPSV 1e-30f
#define CH_J ((LL+1)*NNT)  // 1584
#define SEB_S 2328         // shorts per sEb row (2304 + pad)
#define PD_NT 264          // floats per nt-tile in pD
#define PD_S  (3*PD_NT)    // 792

typedef __attribute__((ext_vector_type(8))) short bf16x8;
typedef __attribute__((ext_vector_type(4))) float f32x4;
typedef __attribute__((ext_vector_type(4))) int   i32x4;

__device__ __forceinline__ int ch_idx(int b, int i, int j, int n) {
    return (((b*LL + i)*(LL+1) + j)*NNT + n);
}
__device__ __forceinline__ unsigned short f2bf(float x) {
    unsigned u = __float_as_uint(x);
    u = (u + 0x7fffu + ((u >> 16) & 1u)) >> 16;   // RNE
    return (unsigned short)u;
}
// EU/EV slab addressing (shorts): [q][r=0..47][k=0..31] bf16, 16B-chunk XOR swizzle
__device__ __forceinline__ int uvt_base(int q, int r, int kc) {
    return q*1536 + ((((r << 2) + kc) ^ (r & 7)) << 3);
}
__device__ __forceinline__ float wavemax(float x) {
    #pragma unroll
    for (int o = 32; o; o >>= 1) x = fmaxf(x, __shfl_xor(x, o));
    return x;
}
// device-scope (cross-XCD-safe) chart access
__device__ __forceinline__ float ch_ld(const float* p) {
    return __hip_atomic_load(p, __ATOMIC_RELAXED, __HIP_MEMORY_SCOPE_AGENT);
}
__device__ __forceinline__ void ch_st(float* p, float v) {
    __hip_atomic_store(p, v, __ATOMIC_RELAXED, __HIP_MEMORY_SCOPE_AGENT);
}

// prep: blocks 0..431 pack W into MFMA B-frag order (e = c*48+b'); blocks
// 432..687 write leaf chart rows + row-max into the chart j=0 column.
// Block 0 additionally zeroes the 256 progress counters.
__global__ void prep_kernel(const float* __restrict__ binary, const int* __restrict__ tokens,
                            const float* __restrict__ lexical, unsigned short* __restrict__ Wp,
                            float* __restrict__ chart, int* __restrict__ prog, int T) {
    if (blockIdx.x < 432) {
        if (blockIdx.x == 0) prog[threadIdx.x] = 0;   // 256 counters
        int idx = blockIdx.x*256 + threadIdx.x;       // 432*256 == 3*72*512
        int j  = idx & 7;
        int l  = (idx >> 3) & 63;
        int ks = (idx >> 9) % KSTEPS;
        int nt = idx / (KSTEPS*512);
        int e = ks*32 + ((l >> 4) << 3) + j;
        int n = nt*16 + (l & 15);
        int bp = e % 48, c = e / 48;
        Wp[idx] = f2bf(fmaxf(binary[n*N2 + bp*48 + c], EPSV));
    } else {
        int row = (blockIdx.x - 432)*4 + (threadIdx.x >> 6);   // 1024 rows
        int lane = threadIdx.x & 63;
        int b = row >> 5, i = row & 31;
        int tok = tokens[b*LL + i];
        float val = (lane < NNT)
            ? __logf(fmaxf(lexical[(size_t)lane*(size_t)T + (size_t)tok], EPSV))
            : -INFINITY;
        float rm = wavemax(val);
        if (lane < NNT) chart[ch_idx(b, i, i+1, lane)] = val;
        if (lane == 0) chart[ch_idx(b, i, 0, i+1)] = rm;   // rmax cache
    }
}

#define MFMA16(A,B,C) __builtin_amdgcn_mfma_f32_16x16x32_bf16(A,B,C,0,0,0)

// loads for split-slots [C*8, C*8+8), clamped to owned splits (kk = rr + t*2)
#define LDCH2(U, V, C)                                                         \
    { _Pragma("unroll")                                                        \
      for (int dt = 0; dt < 8; ++dt) {                                         \
          int t = (C)*8 + dt; int tt = (t < tc) ? t : tc - 1;                  \
          int kk = rr + tt*2;                                                  \
          U[dt] = ch_ld(up + kk*NNT + ln);                                     \
          V[dt] = ch_ld(vp + kk*CH_J + ln);                                    \
      } }

// consume chunk: per-split two-sided shift (args <= 0 -> overflow-free)
#define CONSCH2(U, V, C)                                                       \
    { int pu[4], pv[4];                                                        \
      _Pragma("unroll")                                                        \
      for (int dt = 0; dt < 8; ++dt) {                                         \
          int t = (C)*8 + dt; int tt = (t < tc) ? t : tc - 1;                  \
          int kk = rr + tt*2;                                                  \
          float al = sAl[w][kk];                                               \
          unsigned eu = f2bf(__expf(U[dt] - al));                              \
          unsigned ev = f2bf(__expf(V[dt] + al - M));                          \
          if (dt & 1) { pu[dt>>1] |= (int)(eu << 16); pv[dt>>1] |= (int)(ev << 16); } \
          else        { pu[dt>>1]  = (int)eu;         pv[dt>>1]  = (int)ev; }  \
      }                                                                        \
      if (lane < NNT) {                                                        \
          int ad = uvt_base(w, lane, (C));                                     \
          *(i32x4*)&sUV[ad]         = (i32x4){pu[0],pu[1],pu[2],pu[3]};        \
          *(i32x4*)&sUV[12288 + ad] = (i32x4){pv[0],pv[1],pv[2],pv[3]};        \
      } }

// Single launch: 256 blocks (1/CU), 512 threads. Gang of 8 blocks per batch
// element b; block c owns i = 28-4c .. 31-4c; per level, 2 waves per instance
// (split parity rr). Gang sync via prog[b*8+c] (release/acquire, agent scope).
__global__ __launch_bounds__(512) void inside_kernel(
        const unsigned short* __restrict__ Wp,
        float* __restrict__ chart,
        int* __restrict__ prog,
        float* __restrict__ out) {
    const int g = blockIdx.x;
    const int b = g >> 3, c = g & 7;
    const int i_base = 28 - 4*c;
    const int tid = threadIdx.x, lane = tid & 63, w = tid >> 6;
    const int fr = lane & 15, kg = lane >> 4;
    const int ln = (lane < NNT) ? lane : 0;
    const int q = w >> 1, rr = w & 1;       // instance slot, split parity
    const int i0 = i_base + q;

    __shared__ __align__(16) short sUV[24576];       // EU | EV(+12288)  48 KB
    __shared__ __align__(16) short sEb[16*SEB_S];    //                 74.5 KB
    __shared__ float pD[8*PD_S];                     //                 25.3 KB
    __shared__ float sAl[8][32];                     // per-wave alphas   1 KB

    for (int x = tid; x < 12288; x += 512) ((int*)sUV)[x] = 0;
    for (int x = tid; x < 18624; x += 512) ((int*)sEb)[x] = 0;
    __syncthreads();

    const bf16x8* wp8 = (const bf16x8*)Wp;
    const int kstart = 9*w;

    for (int s = 2; s <= LL; ++s) {
        const int nk = s - 1;

        // permanently idle: publish completion and exit
        if (i_base > LL - s) {
            if (tid == 0)
                __hip_atomic_store(&prog[g], LL, __ATOMIC_RELEASE, __HIP_MEMORY_SCOPE_AGENT);
            return;
        }

        // gang wait: all spans of length <= s-1 of this b complete
        if (s > 2 && tid < 8) {
            const int* pp = &prog[(b << 3) + tid];
            while (__hip_atomic_load(pp, __ATOMIC_ACQUIRE, __HIP_MEMORY_SCOPE_AGENT) < s - 1)
                __builtin_amdgcn_s_sleep(1);
        }
        __syncthreads();   // B0

        const bool active = (i0 <= LL - s);
        const int tc = active ? ((nk - rr + 1) >> 1) : 0;   // owned splits (parity rr)
        float M = -INFINITY;
        f32x4 ea[9];
        #pragma unroll
        for (int z = 0; z < 9; ++z) ea[z] = (f32x4){0.f, 0.f, 0.f, 0.f};

        if (active) {
            // M phase: lane t = split t; alpha/beta from the rmax column
            float al = -INFINITY, bt = -INFINITY;
            if (lane < nk) {
                al = ch_ld(&chart[ch_idx(b, i0, 0, i0 + 1 + lane)]);
                bt = ch_ld(&chart[ch_idx(b, i0 + 1 + lane, 0, i0 + s)]);
            }
            if (lane < 32) sAl[w][lane] = al;
            M = wavemax((lane < nk) ? al + bt : -INFINITY);
        }

        if (tc > 0) {
            const float* up = chart + ch_idx(b, i0, i0 + 1, 0);
            const float* vp = chart + ch_idx(b, i0 + 1, i0 + s, 0);
            float ubA[8], vbA[8], ubB[8], vbB[8];
            LDCH2(ubA, vbA, 0)
            if (tc > 8) { LDCH2(ubB, vbB, 1) }
            CONSCH2(ubA, vbA, 0)
            if (tc > 8) { CONSCH2(ubB, vbB, 1) }

            // stage-1 MFMA: partial E[b'][c] = sum_t EU[t][b'] * EV[t][c]
            bf16x8 A0 = *(const bf16x8*)&sUV[uvt_base(w,  0 + fr, kg)];
            bf16x8 A1 = *(const bf16x8*)&sUV[uvt_base(w, 16 + fr, kg)];
            bf16x8 A2 = *(const bf16x8*)&sUV[uvt_base(w, 32 + fr, kg)];
            #pragma unroll
            for (int jj = 0; jj < 8; ++jj)
                if (kg*8 + jj >= tc) { A0[jj] = 0; A1[jj] = 0; A2[jj] = 0; }
            bf16x8 B0 = *(const bf16x8*)&sUV[12288 + uvt_base(w,  0 + fr, kg)];
            bf16x8 B1 = *(const bf16x8*)&sUV[12288 + uvt_base(w, 16 + fr, kg)];
            bf16x8 B2 = *(const bf16x8*)&sUV[12288 + uvt_base(w, 32 + fr, kg)];
            ea[0] = MFMA16(A0,B0,ea[0]); ea[1] = MFMA16(A0,B1,ea[1]); ea[2] = MFMA16(A0,B2,ea[2]);
            ea[3] = MFMA16(A1,B0,ea[3]); ea[4] = MFMA16(A1,B1,ea[4]); ea[5] = MFMA16(A1,B2,ea[5]);
            ea[6] = MFMA16(A2,B0,ea[6]); ea[7] = MFMA16(A2,B1,ea[7]); ea[8] = MFMA16(A2,B2,ea[8]);
        }

        // pack partial E -> sEb row w (active: zeros if tc==0 so epilogue sums work)
        if (active) {
            #pragma unroll
            for (int mt = 0; mt < 3; ++mt) {
                #pragma unroll
                for (int ct = 0; ct < 3; ++ct) {
                    f32x4 d = ea[mt*3 + ct];
                    int e0 = (ct*16 + fr)*48 + mt*16 + kg*4;
                    unsigned long long lo = (unsigned long long)f2bf(d[0])
                                          | ((unsigned long long)f2bf(d[1]) << 16);
                    unsigned long long hi = (unsigned long long)f2bf(d[2])
                                          | ((unsigned long long)f2bf(d[3]) << 16);
                    *(unsigned long long*)&sEb[w*SEB_S + e0] = lo | (hi << 32);
                }
            }
        }

        // Wp prefetch (3 ksteps)
        bf16x8 wPf[3][3];
        #pragma unroll
        for (int t = 0; t < 3; ++t)
            #pragma unroll
            for (int nt = 0; nt < 3; ++nt)
                wPf[t][nt] = wp8[(nt*KSTEPS + kstart + t)*64 + lane];

        __syncthreads();   // B2: sEb ready

        // stage-2: K-split MFMA GEMM [16 x 2304] x [2304 x 48]
        {
            f32x4 c0 = {0.f,0.f,0.f,0.f}, c1 = c0, c2 = c0;
            #pragma unroll
            for (int t = 0; t < 9; ++t) {
                int ks = kstart + t;
                bf16x8 af = *(const bf16x8*)&sEb[fr*SEB_S + ks*32 + kg*8];
                bf16x8 q0 = (t < 3) ? wPf[t][0] : wp8[(0*KSTEPS + ks)*64 + lane];
                bf16x8 q1 = (t < 3) ? wPf[t][1] : wp8[(1*KSTEPS + ks)*64 + lane];
                bf16x8 q2 = (t < 3) ? wPf[t][2] : wp8[(2*KSTEPS + ks)*64 + lane];
                c0 = MFMA16(af, q0, c0);
                c1 = MFMA16(af, q1, c1);
                c2 = MFMA16(af, q2, c2);
            }
            #pragma unroll
            for (int r2 = 0; r2 < 4; ++r2) {
                int row = kg*4 + r2;
                pD[w*PD_S + 0*PD_NT + row*16 + fr] = c0[r2];
                pD[w*PD_S + 1*PD_NT + row*16 + fr] = c1[r2];
                pD[w*PD_S + 2*PD_NT + row*16 + fr] = c2[r2];
            }
        }
        __syncthreads();   // B3

        // epilogue: wave rr==0 handles its instance q (rows 2q, 2q+1)
        if (active && rr == 0) {
            float sum = 0.f;
            #pragma unroll
            for (int w2 = 0; w2 < 8; ++w2) {
                const float* pp = &pD[w2*PD_S + (ln >> 4)*PD_NT + (ln & 15)];
                sum += pp[(2*q)*16] + pp[(2*q + 1)*16];
            }
            float val = M + __logf(sum);
            float rm = wavemax((lane < NNT) ? val : -INFINITY);
            if (lane < NNT) ch_st(&chart[ch_idx(b, i0, i0 + s, lane)], val);
            if (lane == 0) {
                ch_st(&chart[ch_idx(b, i0, 0, i0 + s)], rm);
                if (s == LL) out[b] = val;
            }
        }
        __syncthreads();   // B4: drain all waves' stores (vmcnt 0 at barrier)

        if (tid == 0)
            __hip_atomic_store(&prog[g], s, __ATOMIC_RELEASE, __HIP_MEMORY_SCOPE_AGENT);
    }
}

extern "C" void kernel_launch(void* const* d_in, const int* in_sizes, int n_in,
                              void* d_out, int out_size, void* d_ws, size_t ws_size,
                              hipStream_t stream) {
    const int*   tokens  = (const int*)d_in[0];
    const float* binary  = (const float*)d_in[1];
    const float* lexical = (const float*)d_in[2];
    float* out = (float*)d_out;

    float* chart = (float*)d_ws;                                   // 6.49 MB
    unsigned short* Wp = (unsigned short*)(chart + (size_t)BB*LL*(LL+1)*NNT);  // 221 KB bf16
    int* prog = (int*)(Wp + 3*KSTEPS*512);                         // 256 counters

    int T = in_sizes[2] / NNT;   // 32000

    prep_kernel<<<688, 256, 0, stream>>>(binary, tokens, lexical, Wp, chart, prog, T);
    inside_kernel<<<256, 512, 0, stream>>>(Wp, chart, prog, out);
}

// Round 11
// 178.189 us; speedup vs baseline: 1.7170x; 1.7170x over previous
//
#include <hip/hip_runtime.h>
#include <math.h>

#define NNT 48
#define LL 32
#define BB 32
#define N2 2304            // 48*48
#define KSTEPS 72          // 2304/32
#define EPSV 1e-30f
#define CH_J ((LL+1)*NNT)  // 1584
#define SEB_S 2328         // shorts per sEb row (2304 + pad)
#define PD_RS 20           // pD row stride (floats): 2-way-free b32 stores
#define PD_T  328          // pD nt-tile stride (floats)
#define PD_W  984          // pD wave stride (floats)

typedef __attribute__((ext_vector_type(8))) short bf16x8;
typedef __attribute__((ext_vector_type(4))) float f32x4;
typedef __attribute__((ext_vector_type(4))) int   i32x4;

__device__ __forceinline__ int ch_idx(int b, int i, int j, int n) {
    return (((b*LL + i)*(LL+1) + j)*NNT + n);
}
__device__ __forceinline__ unsigned short f2bf(float x) {
    unsigned u = __float_as_uint(x);
    u = (u + 0x7fffu + ((u >> 16) & 1u)) >> 16;   // RNE
    return (unsigned short)u;
}
// EU/EV slab addressing (shorts): [q][r=0..47][k=0..31] bf16, 16B-chunk XOR swizzle
__device__ __forceinline__ int uvt_base(int q, int r, int kc) {
    return q*1536 + ((((r << 2) + kc) ^ (r & 7)) << 3);
}
__device__ __forceinline__ float wavemax(float x) {
    #pragma unroll
    for (int o = 32; o; o >>= 1) x = fmaxf(x, __shfl_xor(x, o));
    return x;
}
// cross-XCD-safe (LLC-coherent, L2-bypassing) chart access — RELAXED: no inv/wb
__device__ __forceinline__ float ch_ld(const float* p) {
    return __hip_atomic_load(p, __ATOMIC_RELAXED, __HIP_MEMORY_SCOPE_AGENT);
}
__device__ __forceinline__ void ch_st(float* p, float v) {
    __hip_atomic_store(p, v, __ATOMIC_RELAXED, __HIP_MEMORY_SCOPE_AGENT);
}

// prep: blocks 0..431 pack W into MFMA B-frag order (e = c*48+b'); blocks
// 432..687 write leaf chart rows + row-max into the chart j=0 column.
// Block 0 additionally zeroes the 256 progress counters.
__global__ void prep_kernel(const float* __restrict__ binary, const int* __restrict__ tokens,
                            const float* __restrict__ lexical, unsigned short* __restrict__ Wp,
                            float* __restrict__ chart, int* __restrict__ prog, int T) {
    if (blockIdx.x < 432) {
        if (blockIdx.x == 0) prog[threadIdx.x] = 0;   // 256 counters
        int idx = blockIdx.x*256 + threadIdx.x;       // 432*256 == 3*72*512
        int j  = idx & 7;
        int l  = (idx >> 3) & 63;
        int ks = (idx >> 9) % KSTEPS;
        int nt = idx / (KSTEPS*512);
        int e = ks*32 + ((l >> 4) << 3) + j;
        int n = nt*16 + (l & 15);
        int bp = e % 48, c = e / 48;
        Wp[idx] = f2bf(fmaxf(binary[n*N2 + bp*48 + c], EPSV));
    } else {
        int row = (blockIdx.x - 432)*4 + (threadIdx.x >> 6);   // 1024 rows
        int lane = threadIdx.x & 63;
        int b = row >> 5, i = row & 31;
        int tok = tokens[b*LL + i];
        float val = (lane < NNT)
            ? __logf(fmaxf(lexical[(size_t)lane*(size_t)T + (size_t)tok], EPSV))
            : -INFINITY;
        float rm = wavemax(val);
        if (lane < NNT) chart[ch_idx(b, i, i+1, lane)] = val;
        if (lane == 0) chart[ch_idx(b, i, 0, i+1)] = rm;   // rmax cache
    }
}

#define MFMA16(A,B,C) __builtin_amdgcn_mfma_f32_16x16x32_bf16(A,B,C,0,0,0)

// loads for split-slots [C*8, C*8+8), clamped to owned splits (kk = rr + t*2)
#define LDCH2(U, V, C)                                                         \
    { _Pragma("unroll")                                                        \
      for (int dt = 0; dt < 8; ++dt) {                                         \
          int t = (C)*8 + dt; int tt = (t < tc) ? t : tc - 1;                  \
          int kk = rr + tt*2;                                                  \
          U[dt] = ch_ld(up + kk*NNT + ln);                                     \
          V[dt] = ch_ld(vp + kk*CH_J + ln);                                    \
      } }

// consume chunk: per-split two-sided shift (args <= 0 -> overflow-free)
#define CONSCH2(U, V, C)                                                       \
    { int pu[4], pv[4];                                                        \
      _Pragma("unroll")                                                        \
      for (int dt = 0; dt < 8; ++dt) {                                         \
          int t = (C)*8 + dt; int tt = (t < tc) ? t : tc - 1;                  \
          int kk = rr + tt*2;                                                  \
          float al = sAl[w][kk];                                               \
          unsigned eu = f2bf(__expf(U[dt] - al));                              \
          unsigned ev = f2bf(__expf(V[dt] + al - M));                          \
          if (dt & 1) { pu[dt>>1] |= (int)(eu << 16); pv[dt>>1] |= (int)(ev << 16); } \
          else        { pu[dt>>1]  = (int)eu;         pv[dt>>1]  = (int)ev; }  \
      }                                                                        \
      if (lane < NNT) {                                                        \
          int ad = uvt_base(w, lane, (C));                                     \
          *(i32x4*)&sUV[ad]         = (i32x4){pu[0],pu[1],pu[2],pu[3]};        \
          *(i32x4*)&sUV[12288 + ad] = (i32x4){pv[0],pv[1],pv[2],pv[3]};        \
      } }

// Single worker launch: 256 blocks, 512 threads. Gang of 8 blocks per batch b,
// gang members at blockIdx = b + 32c (same XCD under the %8 mapping — perf
// heuristic only; correctness is agent-scope). Block c owns i = 28-4c..31-4c;
// per level 2 waves per instance (split parity). Sync: prog[b*8+c], RELAXED
// agent-scope; B4's vmcnt drain orders chart stores before the flag store.
__global__ __launch_bounds__(512) void inside_kernel(
        const unsigned short* __restrict__ Wp,
        float* __restrict__ chart,
        int* __restrict__ prog,
        float* __restrict__ out) {
    const int pb = blockIdx.x;
    const int b = pb & 31, c = pb >> 5;     // gang member c on XCD b%8
    const int i_base = 28 - 4*c;
    const int tid = threadIdx.x, lane = tid & 63, w = tid >> 6;
    const int fr = lane & 15, kg = lane >> 4;
    const int ln = (lane < NNT) ? lane : 0;
    const int q = w >> 1, rr = w & 1;       // instance slot, split parity
    const int i0 = i_base + q;
    const int pg = (b << 3) + c;            // progress slot

    __shared__ __align__(16) short sUV[24576];       // EU | EV(+12288)  48 KB
    __shared__ __align__(16) short sEb[16*SEB_S];    //                 74.5 KB
    __shared__ float pD[8*PD_W];                     //                 31.5 KB
    __shared__ float sAl[8][32];                     // per-wave alphas   1 KB

    for (int x = tid; x < 12288; x += 512) ((int*)sUV)[x] = 0;
    for (int x = tid; x < 18624; x += 512) ((int*)sEb)[x] = 0;
    __syncthreads();

    const bf16x8* wp8 = (const bf16x8*)Wp;
    const int kstart = 9*w;

    for (int s = 2; s <= LL; ++s) {
        const int nk = s - 1;

        // permanently idle: publish completion and exit
        if (i_base > LL - s) {
            if (tid == 0)
                __hip_atomic_store(&prog[pg], LL, __ATOMIC_RELAXED, __HIP_MEMORY_SCOPE_AGENT);
            return;
        }

        // gang wait: all spans of length <= s-1 of this b complete (RELAXED poll)
        if (s > 2 && tid < 8) {
            const int* pp = &prog[(b << 3) + tid];
            while (__hip_atomic_load(pp, __ATOMIC_RELAXED, __HIP_MEMORY_SCOPE_AGENT) < s - 1)
                __builtin_amdgcn_s_sleep(1);
        }
        __syncthreads();   // B0

        const bool active = (i0 <= LL - s);
        const int tc = active ? ((nk - rr + 1) >> 1) : 0;   // owned splits (parity rr)
        float M = -INFINITY;
        f32x4 ea[9];
        #pragma unroll
        for (int z = 0; z < 9; ++z) ea[z] = (f32x4){0.f, 0.f, 0.f, 0.f};

        if (tc > 0) {
            const float* up = chart + ch_idx(b, i0, i0 + 1, 0);
            const float* vp = chart + ch_idx(b, i0 + 1, i0 + s, 0);
            float ubA[8], vbA[8], ubB[8], vbB[8];
            // issue ALL split loads upfront (single latency round)...
            LDCH2(ubA, vbA, 0)
            if (tc > 8) { LDCH2(ubB, vbB, 1) }
            // ...and overlap the M phase with their latency
            {
                float al = -INFINITY, bt = -INFINITY;
                if (lane < nk) {
                    al = ch_ld(&chart[ch_idx(b, i0, 0, i0 + 1 + lane)]);
                    bt = ch_ld(&chart[ch_idx(b, i0 + 1 + lane, 0, i0 + s)]);
                }
                if (lane < 32) sAl[w][lane] = al;
                M = wavemax((lane < nk) ? al + bt : -INFINITY);
            }
            CONSCH2(ubA, vbA, 0)
            if (tc > 8) { CONSCH2(ubB, vbB, 1) }

            // stage-1 MFMA: partial E[b'][c] = sum_t EU[t][b'] * EV[t][c]
            bf16x8 A0 = *(const bf16x8*)&sUV[uvt_base(w,  0 + fr, kg)];
            bf16x8 A1 = *(const bf16x8*)&sUV[uvt_base(w, 16 + fr, kg)];
            bf16x8 A2 = *(const bf16x8*)&sUV[uvt_base(w, 32 + fr, kg)];
            #pragma unroll
            for (int jj = 0; jj < 8; ++jj)
                if (kg*8 + jj >= tc) { A0[jj] = 0; A1[jj] = 0; A2[jj] = 0; }
            bf16x8 B0 = *(const bf16x8*)&sUV[12288 + uvt_base(w,  0 + fr, kg)];
            bf16x8 B1 = *(const bf16x8*)&sUV[12288 + uvt_base(w, 16 + fr, kg)];
            bf16x8 B2 = *(const bf16x8*)&sUV[12288 + uvt_base(w, 32 + fr, kg)];
            ea[0] = MFMA16(A0,B0,ea[0]); ea[1] = MFMA16(A0,B1,ea[1]); ea[2] = MFMA16(A0,B2,ea[2]);
            ea[3] = MFMA16(A1,B0,ea[3]); ea[4] = MFMA16(A1,B1,ea[4]); ea[5] = MFMA16(A1,B2,ea[5]);
            ea[6] = MFMA16(A2,B0,ea[6]); ea[7] = MFMA16(A2,B1,ea[7]); ea[8] = MFMA16(A2,B2,ea[8]);
        }

        // pack partial E -> sEb row w (stale inactive rows are computed-but-ignored)
        if (active) {
            #pragma unroll
            for (int mt = 0; mt < 3; ++mt) {
                #pragma unroll
                for (int ct = 0; ct < 3; ++ct) {
                    f32x4 d = ea[mt*3 + ct];
                    int e0 = (ct*16 + fr)*48 + mt*16 + kg*4;
                    unsigned long long lo = (unsigned long long)f2bf(d[0])
                                          | ((unsigned long long)f2bf(d[1]) << 16);
                    unsigned long long hi = (unsigned long long)f2bf(d[2])
                                          | ((unsigned long long)f2bf(d[3]) << 16);
                    *(unsigned long long*)&sEb[w*SEB_S + e0] = lo | (hi << 32);
                }
            }
        }

        // Wp prefetch (3 ksteps; L2-resident now that nothing invalidates L2)
        bf16x8 wPf[3][3];
        #pragma unroll
        for (int t = 0; t < 3; ++t)
            #pragma unroll
            for (int nt = 0; nt < 3; ++nt)
                wPf[t][nt] = wp8[(nt*KSTEPS + kstart + t)*64 + lane];

        __syncthreads();   // B2: sEb ready

        // stage-2: K-split MFMA GEMM [16 x 2304] x [2304 x 48]
        {
            f32x4 c0 = {0.f,0.f,0.f,0.f}, c1 = c0, c2 = c0;
            #pragma unroll
            for (int t = 0; t < 9; ++t) {
                int ks = kstart + t;
                bf16x8 af = *(const bf16x8*)&sEb[fr*SEB_S + ks*32 + kg*8];
                bf16x8 q0 = (t < 3) ? wPf[t][0] : wp8[(0*KSTEPS + ks)*64 + lane];
                bf16x8 q1 = (t < 3) ? wPf[t][1] : wp8[(1*KSTEPS + ks)*64 + lane];
                bf16x8 q2 = (t < 3) ? wPf[t][2] : wp8[(2*KSTEPS + ks)*64 + lane];
                c0 = MFMA16(af, q0, c0);
                c1 = MFMA16(af, q1, c1);
                c2 = MFMA16(af, q2, c2);
            }
            #pragma unroll
            for (int r2 = 0; r2 < 4; ++r2) {
                int row = kg*4 + r2;
                pD[w*PD_W + 0*PD_T + row*PD_RS + fr] = c0[r2];
                pD[w*PD_W + 1*PD_T + row*PD_RS + fr] = c1[r2];
                pD[w*PD_W + 2*PD_T + row*PD_RS + fr] = c2[r2];
            }
        }
        __syncthreads();   // B3

        // epilogue: wave rr==0 handles its instance q (rows 2q, 2q+1)
        if (active && rr == 0) {
            float sum = 0.f;
            #pragma unroll
            for (int w2 = 0; w2 < 8; ++w2) {
                const float* pp = &pD[w2*PD_W + (ln >> 4)*PD_T + (ln & 15)];
                sum += pp[(2*q)*PD_RS] + pp[(2*q + 1)*PD_RS];
            }
            float val = M + __logf(sum);
            float rm = wavemax((lane < NNT) ? val : -INFINITY);
            if (lane < NNT) ch_st(&chart[ch_idx(b, i0, i0 + s, lane)], val);
            if (lane == 0) {
                ch_st(&chart[ch_idx(b, i0, 0, i0 + s)], rm);
                if (s == LL) out[b] = val;
            }
        }
        __syncthreads();   // B4: vmcnt(0) drain -> all chart stores at LLC

        if (tid == 0)
            __hip_atomic_store(&prog[pg], s, __ATOMIC_RELAXED, __HIP_MEMORY_SCOPE_AGENT);
    }
}

extern "C" void kernel_launch(void* const* d_in, const int* in_sizes, int n_in,
                              void* d_out, int out_size, void* d_ws, size_t ws_size,
                              hipStream_t stream) {
    const int*   tokens  = (const int*)d_in[0];
    const float* binary  = (const float*)d_in[1];
    const float* lexical = (const float*)d_in[2];
    float* out = (float*)d_out;

    float* chart = (float*)d_ws;                                   // 6.49 MB
    unsigned short* Wp = (unsigned short*)(chart + (size_t)BB*LL*(LL+1)*NNT);  // 221 KB bf16
    int* prog = (int*)(Wp + 3*KSTEPS*512);                         // 256 counters

    int T = in_sizes[2] / NNT;   // 32000

    prep_kernel<<<688, 256, 0, stream>>>(binary, tokens, lexical, Wp, chart, prog, T);
    inside_kernel<<<256, 512, 0, stream>>>(Wp, chart, prog, out);
}

// Round 12
// 163.489 us; speedup vs baseline: 1.8713x; 1.0899x over previous
//
#include <hip/hip_runtime.h>
#include <math.h>

#define NNT 48
#define LL 32
#define BB 32
#define N2 2304            // 48*48
#define KSTEPS 72          // 2304/32
#define EPSV 1e-30f
#define CH_J ((LL+1)*NNT)  // 1584
#define SEB_S 2328         // shorts per sEb row (2304 + pad)
#define PD_RS 20           // pD row stride (floats)
#define PD_T  328          // pD nt-tile stride (floats)
#define PD_W  984          // pD wave stride (floats)
#define NCELL (BB*LL*(LL+1)*NNT)   // 1,622,016 chart cells

typedef __attribute__((ext_vector_type(8))) short bf16x8;
typedef __attribute__((ext_vector_type(4))) float f32x4;
typedef __attribute__((ext_vector_type(4))) int   i32x4;

__device__ __forceinline__ int ch_idx(int b, int i, int j, int n) {
    return (((b*LL + i)*(LL+1) + j)*NNT + n);
}
__device__ __forceinline__ unsigned short f2bf(float x) {
    unsigned u = __float_as_uint(x);
    u = (u + 0x7fffu + ((u >> 16) & 1u)) >> 16;   // RNE
    return (unsigned short)u;
}
// EU/EV slab addressing (shorts): [q][r=0..47][k=0..31] bf16, 16B-chunk XOR swizzle
__device__ __forceinline__ int uvt_base(int q, int r, int kc) {
    return q*1536 + ((((r << 2) + kc) ^ (r & 7)) << 3);
}
__device__ __forceinline__ float wavemax(float x) {
    #pragma unroll
    for (int o = 32; o; o >>= 1) x = fmaxf(x, __shfl_xor(x, o));
    return x;
}
// cross-XCD-safe (LLC-coherent, L2-bypassing) chart access — RELAXED, no inv/wb
__device__ __forceinline__ float ch_ld(const float* p) {
    return __hip_atomic_load(p, __ATOMIC_RELAXED, __HIP_MEMORY_SCOPE_AGENT);
}
__device__ __forceinline__ void ch_st(float* p, float v) {
    __hip_atomic_store(p, v, __ATOMIC_RELAXED, __HIP_MEMORY_SCOPE_AGENT);
}

// prep: [0,432) pack W into MFMA B-frag order; [432,688) leaf rows + leaf rmax;
// [688,7024) write -inf sentinels into every non-leaf chart cell (data-as-flag).
__global__ void prep_kernel(const float* __restrict__ binary, const int* __restrict__ tokens,
                            const float* __restrict__ lexical, unsigned short* __restrict__ Wp,
                            float* __restrict__ chart, int T) {
    if (blockIdx.x < 432) {
        int idx = blockIdx.x*256 + threadIdx.x;       // 432*256 == 3*72*512
        int j  = idx & 7;
        int l  = (idx >> 3) & 63;
        int ks = (idx >> 9) % KSTEPS;
        int nt = idx / (KSTEPS*512);
        int e = ks*32 + ((l >> 4) << 3) + j;
        int n = nt*16 + (l & 15);
        int bp = e % 48, c = e / 48;
        Wp[idx] = f2bf(fmaxf(binary[n*N2 + bp*48 + c], EPSV));
    } else if (blockIdx.x < 688) {
        int row = (blockIdx.x - 432)*4 + (threadIdx.x >> 6);   // 1024 rows
        int lane = threadIdx.x & 63;
        int b = row >> 5, i = row & 31;
        int tok = tokens[b*LL + i];
        float val = (lane < NNT)
            ? __logf(fmaxf(lexical[(size_t)lane*(size_t)T + (size_t)tok], EPSV))
            : -INFINITY;
        float rm = wavemax(val);
        if (lane < NNT) chart[ch_idx(b, i, i+1, lane)] = val;
        if (lane == 0) chart[ch_idx(b, i, 0, i+1)] = rm;   // leaf rmax
    } else {
        int idx = (blockIdx.x - 688)*256 + threadIdx.x;
        if (idx < NCELL) {
            int n = idx % NNT;
            int r = idx / NNT;
            int j = r % (LL + 1);
            int i = (r / (LL + 1)) % LL;
            // skip leaf rows and leaf rmax cells (written by the leaf blocks)
            if (j != i + 1 && !(j == 0 && n == i + 1))
                chart[idx] = -INFINITY;
        }
    }
}

#define MFMA16(A,B,C) __builtin_amdgcn_mfma_f32_16x16x32_bf16(A,B,C,0,0,0)

// own-row (left child) loads for split-slots [C*8, C*8+8) (kk = rr + t*2)
#define LDU(U, C)                                                              \
    { _Pragma("unroll")                                                        \
      for (int dt = 0; dt < 8; ++dt) {                                         \
          int t = (C)*8 + dt; int tt = (t < tc) ? t : tc - 1;                  \
          int kk = rr + tt*2;                                                  \
          U[dt] = ch_ld(up + kk*NNT + ln);                                     \
      } }
// right-child row loads (spun on: sentinel -inf until producer's value lands)
#define LDV(V, C)                                                              \
    { _Pragma("unroll")                                                        \
      for (int dt = 0; dt < 8; ++dt) {                                         \
          int t = (C)*8 + dt; int tt = (t < tc) ? t : tc - 1;                  \
          int kk = rr + tt*2;                                                  \
          V[dt] = ch_ld(vp + kk*CH_J + ln);                                    \
      } }

// consume chunk: per-split two-sided shift (args <= 0 -> overflow-free)
#define CONSCH(U, V, C)                                                        \
    { int pu[4], pv[4];                                                        \
      _Pragma("unroll")                                                        \
      for (int dt = 0; dt < 8; ++dt) {                                         \
          int t = (C)*8 + dt; int tt = (t < tc) ? t : tc - 1;                  \
          int kk = rr + tt*2;                                                  \
          float al = sRm[q][kk + 1];                                           \
          unsigned eu = f2bf(__expf(U[dt] - al));                              \
          unsigned ev = f2bf(__expf(V[dt] + al - M));                          \
          if (dt & 1) { pu[dt>>1] |= (int)(eu << 16); pv[dt>>1] |= (int)(ev << 16); } \
          else        { pu[dt>>1]  = (int)eu;         pv[dt>>1]  = (int)ev; }  \
      }                                                                        \
      if (lane < NNT) {                                                        \
          int ad = uvt_base(w, lane, (C));                                     \
          *(i32x4*)&sUV[ad]         = (i32x4){pu[0],pu[1],pu[2],pu[3]};        \
          *(i32x4*)&sUV[12288 + ad] = (i32x4){pv[0],pv[1],pv[2],pv[3]};        \
      } }

// 256 blocks, 512 thr. Gang of 8 blocks per batch b at blockIdx = b + 32c
// (same XCD under %8 — perf heuristic only). Block c owns i = 28-4c..31-4c;
// 2 waves per instance (split parity). Sync: SENTINEL SPIN — consumers spin
// directly on the -inf-initialized chart cells they need (each cell is
// self-validating; written exactly once). No flags, no gang barrier.
// Deps flow block c' <= c only -> acyclic -> no deadlock.
__global__ __launch_bounds__(512) void inside_kernel(
        const unsigned short* __restrict__ Wp,
        float* __restrict__ chart,
        float* __restrict__ out) {
    const int pb = blockIdx.x;
    const int b = pb & 31, c = pb >> 5;
    const int i_base = 28 - 4*c;
    const int tid = threadIdx.x, lane = tid & 63, w = tid >> 6;
    const int fr = lane & 15, kg = lane >> 4;
    const int ln = (lane < NNT) ? lane : 0;
    const int q = w >> 1, rr = w & 1;       // instance slot, split parity
    const int i0 = i_base + q;

    __shared__ __align__(16) short sUV[24576];       // EU | EV(+12288)  48 KB
    __shared__ __align__(16) short sEb[16*SEB_S];    //                 74.5 KB
    __shared__ float pD[8*PD_W];                     //                 31.5 KB
    __shared__ float sRm[4][33];                     // own-row maxima cache

    for (int x = tid; x < 12288; x += 512) ((int*)sUV)[x] = 0;
    for (int x = tid; x < 18624; x += 512) ((int*)sEb)[x] = 0;
    if (tid < 4)   // own leaf rmax -> cache
        sRm[tid][1] = ch_ld(&chart[ch_idx(b, i_base + tid, 0, i_base + tid + 1)]);
    __syncthreads();

    const bf16x8* wp8 = (const bf16x8*)Wp;
    const int kstart = 9*w;

    for (int s = 2; s <= LL; ++s) {
        const int nk = s - 1;
        if (i_base > LL - s) return;                       // block done forever

        const bool active = (i0 <= LL - s);
        const int tc = active ? ((nk - rr + 1) >> 1) : 0;  // owned splits (parity rr)
        float M = -INFINITY;
        f32x4 ea[9];
        #pragma unroll
        for (int z = 0; z < 9; ++z) ea[z] = (f32x4){0.f, 0.f, 0.f, 0.f};

        if (tc > 0) {
            const float* up = chart + ch_idx(b, i0, i0 + 1, 0);
            const float* vp = chart + ch_idx(b, i0 + 1, i0 + s, 0);
            const float* bp = chart + ch_idx(b, i0 + 1, 0, i0 + s);  // beta col

            float uu0[8], uu1[8], vv0[8], vv1[8];
            LDU(uu0, 0)
            if (tc > 8) { LDU(uu1, 1) }

            // sentinel spin: beta (all splits, for M) + own-parity v rows
            float bt = (lane < nk) ? ch_ld(bp + lane*CH_J) : 0.f;
            LDV(vv0, 0)
            if (tc > 8) { LDV(vv1, 1) }
            for (;;) {
                bool bad = (lane < nk) && (bt == -INFINITY);
                #pragma unroll
                for (int dt = 0; dt < 8; ++dt) bad |= (vv0[dt] == -INFINITY);
                if (tc > 8) {
                    #pragma unroll
                    for (int dt = 0; dt < 8; ++dt) bad |= (vv1[dt] == -INFINITY);
                }
                if (!__any(bad)) break;
                bt = (lane < nk) ? ch_ld(bp + lane*CH_J) : 0.f;
                LDV(vv0, 0)
                if (tc > 8) { LDV(vv1, 1) }
            }

            // M = max_k (alpha_k + beta_k); alpha from LDS cache
            {
                float al = (lane < nk) ? sRm[q][lane + 1] : -INFINITY;
                M = wavemax((lane < nk) ? al + bt : -INFINITY);
            }

            CONSCH(uu0, vv0, 0)
            if (tc > 8) { CONSCH(uu1, vv1, 1) }

            // stage-1 MFMA: partial E[b'][c] = sum_t EU[t][b'] * EV[t][c]
            bf16x8 A0 = *(const bf16x8*)&sUV[uvt_base(w,  0 + fr, kg)];
            bf16x8 A1 = *(const bf16x8*)&sUV[uvt_base(w, 16 + fr, kg)];
            bf16x8 A2 = *(const bf16x8*)&sUV[uvt_base(w, 32 + fr, kg)];
            #pragma unroll
            for (int jj = 0; jj < 8; ++jj)
                if (kg*8 + jj >= tc) { A0[jj] = 0; A1[jj] = 0; A2[jj] = 0; }
            bf16x8 B0 = *(const bf16x8*)&sUV[12288 + uvt_base(w,  0 + fr, kg)];
            bf16x8 B1 = *(const bf16x8*)&sUV[12288 + uvt_base(w, 16 + fr, kg)];
            bf16x8 B2 = *(const bf16x8*)&sUV[12288 + uvt_base(w, 32 + fr, kg)];
            ea[0] = MFMA16(A0,B0,ea[0]); ea[1] = MFMA16(A0,B1,ea[1]); ea[2] = MFMA16(A0,B2,ea[2]);
            ea[3] = MFMA16(A1,B0,ea[3]); ea[4] = MFMA16(A1,B1,ea[4]); ea[5] = MFMA16(A1,B2,ea[5]);
            ea[6] = MFMA16(A2,B0,ea[6]); ea[7] = MFMA16(A2,B1,ea[7]); ea[8] = MFMA16(A2,B2,ea[8]);
        }

        // pack partial E -> sEb row w
        if (active) {
            #pragma unroll
            for (int mt = 0; mt < 3; ++mt) {
                #pragma unroll
                for (int ct = 0; ct < 3; ++ct) {
                    f32x4 d = ea[mt*3 + ct];
                    int e0 = (ct*16 + fr)*48 + mt*16 + kg*4;
                    unsigned long long lo = (unsigned long long)f2bf(d[0])
                                          | ((unsigned long long)f2bf(d[1]) << 16);
                    unsigned long long hi = (unsigned long long)f2bf(d[2])
                                          | ((unsigned long long)f2bf(d[3]) << 16);
                    *(unsigned long long*)&sEb[w*SEB_S + e0] = lo | (hi << 32);
                }
            }
        }

        // Wp prefetch (3 ksteps; L2-resident)
        bf16x8 wPf[3][3];
        #pragma unroll
        for (int t = 0; t < 3; ++t)
            #pragma unroll
            for (int nt = 0; nt < 3; ++nt)
                wPf[t][nt] = wp8[(nt*KSTEPS + kstart + t)*64 + lane];

        __syncthreads();   // B2: sEb ready

        // stage-2: K-split MFMA GEMM [16 x 2304] x [2304 x 48]
        {
            f32x4 c0 = {0.f,0.f,0.f,0.f}, c1 = c0, c2 = c0;
            #pragma unroll
            for (int t = 0; t < 9; ++t) {
                int ks = kstart + t;
                bf16x8 af = *(const bf16x8*)&sEb[fr*SEB_S + ks*32 + kg*8];
                bf16x8 q0 = (t < 3) ? wPf[t][0] : wp8[(0*KSTEPS + ks)*64 + lane];
                bf16x8 q1 = (t < 3) ? wPf[t][1] : wp8[(1*KSTEPS + ks)*64 + lane];
                bf16x8 q2 = (t < 3) ? wPf[t][2] : wp8[(2*KSTEPS + ks)*64 + lane];
                c0 = MFMA16(af, q0, c0);
                c1 = MFMA16(af, q1, c1);
                c2 = MFMA16(af, q2, c2);
            }
            #pragma unroll
            for (int r2 = 0; r2 < 4; ++r2) {
                int row = kg*4 + r2;
                pD[w*PD_W + 0*PD_T + row*PD_RS + fr] = c0[r2];
                pD[w*PD_W + 1*PD_T + row*PD_RS + fr] = c1[r2];
                pD[w*PD_W + 2*PD_T + row*PD_RS + fr] = c2[r2];
            }
        }
        __syncthreads();   // B3

        // epilogue: wave rr==0 of instance q -> publish row + rmax (self-validating)
        if (active && rr == 0) {
            float sum = 0.f;
            #pragma unroll
            for (int w2 = 0; w2 < 8; ++w2) {
                const float* pp = &pD[w2*PD_W + (ln >> 4)*PD_T + (ln & 15)];
                sum += pp[(2*q)*PD_RS] + pp[(2*q + 1)*PD_RS];
            }
            float val = M + __logf(sum);
            float rm = wavemax((lane < NNT) ? val : -INFINITY);
            if (lane < NNT) ch_st(&chart[ch_idx(b, i0, i0 + s, lane)], val);
            if (lane == 0) {
                ch_st(&chart[ch_idx(b, i0, 0, i0 + s)], rm);
                sRm[q][s] = rm;
                if (s == LL) out[b] = val;
            }
        }
        __syncthreads();   // B4: sRm visible + sEb/pD/sUV reuse safe
    }
}

extern "C" void kernel_launch(void* const* d_in, const int* in_sizes, int n_in,
                              void* d_out, int out_size, void* d_ws, size_t ws_size,
                              hipStream_t stream) {
    const int*   tokens  = (const int*)d_in[0];
    const float* binary  = (const float*)d_in[1];
    const float* lexical = (const float*)d_in[2];
    float* out = (float*)d_out;

    float* chart = (float*)d_ws;                                   // 6.49 MB
    unsigned short* Wp = (unsigned short*)(chart + (size_t)NCELL); // 221 KB bf16

    int T = in_sizes[2] / NNT;   // 32000

    int fill_blocks = (NCELL + 255)/256;                           // 6336
    prep_kernel<<<688 + fill_blocks, 256, 0, stream>>>(binary, tokens, lexical, Wp, chart, T);
    inside_kernel<<<256, 512, 0, stream>>>(Wp, chart, out);
}